// Round 4
// baseline (234.149 us; speedup 1.0000x reference)
//
#include <hip/hip_runtime.h>

// NMS 2D, 3x3 window, replicate padding, center excluded, max seeded with 0.
// x: (8, 64, 256, 256) fp32.  out[p] = x[p] if x[p] > max(0, 8 neighbors) else 0.
//
// R4: burst-load structure. R1-R3 all plateaued at ~80 us / 2.6 TB/s with
// VGPR=24..32 — the compiler kept re-serializing loads into a register-thrifty
// rolling chain (~1-2 loads in flight/wave). The harness's own fill kernel
// sustains 6.7 TB/s at 9% occupancy via deep bursts of independent memory ops.
// Force that shape: each wave owns 16 output rows, issues 18 independent
// 16B row-loads back-to-back (18 KB outstanding), sched_barrier(0) pins the
// burst before any compute, then a rolling separable-max pipeline + 16 plain
// float4 stores. One group per wave, nothing loop-carried.

#define NMS_H 256
#define NMS_W 256
#define PLANE (NMS_H * NMS_W)
#define ROWS 16

typedef float f4_t __attribute__((ext_vector_type(4)));

struct HV {
    float4 h;   // horizontal max-of-3 per pixel (includes center)
    float4 lr;  // horizontal max of left+right only (center excluded)
};

__device__ __forceinline__ HV rowmax(const float4 v, const int tx) {
    float l = __shfl_up(v.w, 1, 64);    // last elem of lane tx-1
    float r = __shfl_down(v.x, 1, 64);  // first elem of lane tx+1
    if (tx == 0)  l = v.x;              // replicate pad left edge
    if (tx == 63) r = v.w;              // replicate pad right edge
    HV o;
    o.h.x = fmaxf(l,   fmaxf(v.x, v.y));
    o.h.y = fmaxf(v.x, fmaxf(v.y, v.z));
    o.h.z = fmaxf(v.y, fmaxf(v.z, v.w));
    o.h.w = fmaxf(v.z, fmaxf(v.w, r));
    o.lr.x = fmaxf(l,   v.y);
    o.lr.y = fmaxf(v.x, v.z);
    o.lr.z = fmaxf(v.y, v.w);
    o.lr.w = fmaxf(v.z, r);
    return o;
}

__global__ __launch_bounds__(256) void nms2d_kernel(const float* __restrict__ x,
                                                    float* __restrict__ out) {
    // One wave (64 lanes x float4) spans a full 256-px row.
    const int tx   = threadIdx.x;
    const int col4 = tx * 4;
    const int gid  = blockIdx.x * blockDim.y + threadIdx.y;  // 8192 groups
    const int plane_idx = gid >> 4;          // 512 planes (N*C)
    const int r0        = (gid & 15) * ROWS; // 16 groups of 16 rows per plane

    const float* pl = x   + (size_t)plane_idx * PLANE;
    float*       op = out + (size_t)plane_idx * PLANE;

    // Burst: 18 independent row loads (rows r0-1 .. r0+16, clamped).
    float4 v[ROWS + 2];
    #pragma unroll
    for (int i = 0; i < ROWS + 2; ++i) {
        const int r = min(max(r0 + i - 1, 0), NMS_H - 1);
        v[i] = *reinterpret_cast<const float4*>(pl + r * NMS_W + col4);
    }
    // Pin the whole load burst before any compute — defeats the compiler's
    // register-minimal re-serialization seen in R1-R3 (VGPR=24/32).
    __builtin_amdgcn_sched_barrier(0);

    HV a = rowmax(v[0], tx);
    HV b = rowmax(v[1], tx);

    #pragma unroll
    for (int i = 0; i < ROWS; ++i) {
        HV c = rowmax(v[i + 2], tx);
        const float4 ctr = v[i + 1];
        f4_t o;
        float m;
        m = fmaxf(0.0f, fmaxf(fmaxf(a.h.x, c.h.x), b.lr.x)); o.x = (ctr.x > m) ? ctr.x : 0.0f;
        m = fmaxf(0.0f, fmaxf(fmaxf(a.h.y, c.h.y), b.lr.y)); o.y = (ctr.y > m) ? ctr.y : 0.0f;
        m = fmaxf(0.0f, fmaxf(fmaxf(a.h.z, c.h.z), b.lr.z)); o.z = (ctr.z > m) ? ctr.z : 0.0f;
        m = fmaxf(0.0f, fmaxf(fmaxf(a.h.w, c.h.w), b.lr.w)); o.w = (ctr.w > m) ? ctr.w : 0.0f;

        *reinterpret_cast<f4_t*>(op + (r0 + i) * NMS_W + col4) = o;

        a = b; b = c;
    }
}

extern "C" void kernel_launch(void* const* d_in, const int* in_sizes, int n_in,
                              void* d_out, int out_size, void* d_ws, size_t ws_size,
                              hipStream_t stream) {
    const float* x = (const float*)d_in[0];
    float* out = (float*)d_out;

    // 8192 groups (512 planes x 16 strips), one per wave: 2048 blocks x 4 waves.
    // Consecutive waves in a block own adjacent strips -> halo rows hit L1.
    dim3 block(64, 4);
    dim3 grid(2048);
    nms2d_kernel<<<grid, block, 0, stream>>>(x, out);
}

// Round 5
// 228.710 us; speedup vs baseline: 1.0238x; 1.0238x over previous
//
#include <hip/hip_runtime.h>

// NMS 2D, 3x3 window, replicate padding, center excluded, max seeded with 0.
// x: (8, 64, 256, 256) fp32.  out[p] = x[p] if x[p] > max(0, 8 neighbors) else 0.
//
// R5: direct-to-LDS staging. R1-R4 (register-resident, all ~80-85 us, 2.5 TB/s)
// proved the compiler ALWAYS re-serializes VGPR loads into a latency chain
// (~340 cyc/row-load/wave, MLP~1-2). global_load_lds DMA is fire-and-forget
// (no dest VGPR, vmcnt-tracked) so the burst of 18 row-DMAs per block cannot
// be serialized -> ~18 KB in flight per block, ~100+ KB per CU. This is the
// proven m97 GEMM staging path. Phase 2: ds_read_b128 rows + shuffle halo +
// separable max DAG + plain float4 stores.

#define NMS_H 256
#define NMS_W 256
#define PLANE (NMS_H * NMS_W)
#define STRIP 16             // output rows per block
#define LROWS (STRIP + 2)    // staged rows incl. vertical halo

typedef float f4_t __attribute__((ext_vector_type(4)));

struct HV {
    float4 h;   // horizontal max-of-3 per pixel (includes center)
    float4 lr;  // horizontal max of left+right only (center excluded)
};

__device__ __forceinline__ HV rowmax(const float4 v, const int tx) {
    float l = __shfl_up(v.w, 1, 64);    // last elem of lane tx-1
    float r = __shfl_down(v.x, 1, 64);  // first elem of lane tx+1
    if (tx == 0)  l = v.x;              // replicate pad left edge
    if (tx == 63) r = v.w;              // replicate pad right edge
    HV o;
    o.h.x = fmaxf(l,   fmaxf(v.x, v.y));
    o.h.y = fmaxf(v.x, fmaxf(v.y, v.z));
    o.h.z = fmaxf(v.y, fmaxf(v.z, v.w));
    o.h.w = fmaxf(v.z, fmaxf(v.w, r));
    o.lr.x = fmaxf(l,   v.y);
    o.lr.y = fmaxf(v.x, v.z);
    o.lr.z = fmaxf(v.y, v.w);
    o.lr.w = fmaxf(v.z, r);
    return o;
}

__global__ __launch_bounds__(256) void nms2d_kernel(const float* __restrict__ x,
                                                    float* __restrict__ out) {
    __shared__ float lds[LROWS * NMS_W];   // 18 KB

    const int tx   = threadIdx.x;   // 0..63, one float4 column-group
    const int ty   = threadIdx.y;   // 0..3, wave id
    const int col4 = tx * 4;
    const int blk  = blockIdx.x;
    const int plane_idx = blk >> 4;           // 512 planes (N*C)
    const int r0        = (blk & 15) * STRIP; // 16 strips of 16 rows

    const float* pl = x   + (size_t)plane_idx * PLANE;
    float*       op = out + (size_t)plane_idx * PLANE;

    // ---- Phase 1: DMA 18 rows (r0-1 .. r0+16, clamped) into LDS. ----
    // One global_load_lds_dwordx4 per row per wave: 64 lanes x 16 B = 1 KB,
    // landing at wave-uniform LDS base + lane*16 (contiguous row). No VGPR
    // destination => compiler cannot serialize the burst.
    #pragma unroll
    for (int j = ty; j < LROWS; j += 4) {
        const int r = min(max(r0 + j - 1, 0), NMS_H - 1);
        const __attribute__((address_space(1))) float* g =
            (const __attribute__((address_space(1))) float*)(pl + r * NMS_W + col4);
        __attribute__((address_space(3))) float* l =
            (__attribute__((address_space(3))) float*)(&lds[j * NMS_W]);
        __builtin_amdgcn_global_load_lds(g, l, 16, 0, 0);
    }
    __syncthreads();   // drains vmcnt (global_load_lds) before LDS reads

    // ---- Phase 2: each wave computes 4 output rows from LDS. ----
    // Output row r0 + ty*4 + i  (i=0..3) -> lds center row ty*4 + i + 1;
    // wave needs lds rows ty*4 .. ty*4+5.
    const int base = ty * 4;
    float4 v[6];
    #pragma unroll
    for (int i = 0; i < 6; ++i)
        v[i] = *reinterpret_cast<const float4*>(&lds[(base + i) * NMS_W + col4]);

    HV m[6];
    #pragma unroll
    for (int i = 0; i < 6; ++i) m[i] = rowmax(v[i], tx);

    #pragma unroll
    for (int i = 0; i < 4; ++i) {
        const float4 ctr = v[i + 1];
        const float4 ha = m[i].h, hb = m[i + 2].h, lc = m[i + 1].lr;
        f4_t o;
        float mm;
        mm = fmaxf(0.0f, fmaxf(fmaxf(ha.x, hb.x), lc.x)); o.x = (ctr.x > mm) ? ctr.x : 0.0f;
        mm = fmaxf(0.0f, fmaxf(fmaxf(ha.y, hb.y), lc.y)); o.y = (ctr.y > mm) ? ctr.y : 0.0f;
        mm = fmaxf(0.0f, fmaxf(fmaxf(ha.z, hb.z), lc.z)); o.z = (ctr.z > mm) ? ctr.z : 0.0f;
        mm = fmaxf(0.0f, fmaxf(fmaxf(ha.w, hb.w), lc.w)); o.w = (ctr.w > mm) ? ctr.w : 0.0f;
        *reinterpret_cast<f4_t*>(op + (r0 + base + i) * NMS_W + col4) = o;
    }
}

extern "C" void kernel_launch(void* const* d_in, const int* in_sizes, int n_in,
                              void* d_out, int out_size, void* d_ws, size_t ws_size,
                              hipStream_t stream) {
    const float* x = (const float*)d_in[0];
    float* out = (float*)d_out;

    // 512 planes x 16 strips = 8192 blocks (32/CU, ~6-8 resident at 18 KB LDS).
    dim3 block(64, 4);
    dim3 grid(8192);
    nms2d_kernel<<<grid, block, 0, stream>>>(x, out);
}